// Round 1
// baseline (464.489 us; speedup 1.0000x reference)
//
#include <hip/hip_runtime.h>

// Problem constants (B,C,H,W) = (4,64,512,512), labels in [0,1024)
#define NB 4
#define NC 64
#define HW (512*512)
#define NSEG 1024
#define BK (NB*NSEG)          // 4096 segments total
#define CG 16                 // channels per group
#define NCG (NC/CG)           // 4 channel groups
#define CHUNKS 32             // pixel chunks per (b,cg)
#define CHUNK_PIX (HW/CHUNKS) // 8192 pixels per block

// workspace layout in 32-bit words
#define OFF_SUMS   0                  // float[BK*NC]   = 262144
#define OFF_CNT    (BK*NC)            // int[BK]        = 4096
#define OFF_MAX    (OFF_CNT + BK)     // int[1]
#define ZERO_WORDS (OFF_MAX + 1)
#define OFF_SCALED 270336             // float[BK*NC] (aligned region)

#define WEIGHT 0.1f
#define EPSV   1e-5f

__global__ void k_zero(unsigned int* __restrict__ ws) {
    int i = blockIdx.x * blockDim.x + threadIdx.x;
    int stride = gridDim.x * blockDim.x;
    for (; i < ZERO_WORDS; i += stride) ws[i] = 0u;
}

// Per-block label histogram + max. grid = NB*128 blocks of 256 threads,
// each block: 2048 pixels.
__global__ void k_hist(const int* __restrict__ sup, int* __restrict__ ws) {
    __shared__ int hist[NSEG];
    __shared__ int bmax;
    const int tid = threadIdx.x;
    for (int i = tid; i < NSEG; i += 256) hist[i] = 0;
    if (tid == 0) bmax = 0;
    __syncthreads();

    const int bid   = blockIdx.x;
    const int b     = bid >> 7;       // 128 chunks per image
    const int chunk = bid & 127;
    const int4* base = (const int4*)(sup + (size_t)b * HW + chunk * 2048);

    int lmax = 0;
    #pragma unroll
    for (int it = 0; it < 2; ++it) {
        int4 l4 = base[it * 256 + tid];
        atomicAdd(&hist[l4.x], 1);
        atomicAdd(&hist[l4.y], 1);
        atomicAdd(&hist[l4.z], 1);
        atomicAdd(&hist[l4.w], 1);
        lmax = max(lmax, max(max(l4.x, l4.y), max(l4.z, l4.w)));
    }
    atomicMax(&bmax, lmax);
    __syncthreads();

    int* counts = ws + OFF_CNT;
    for (int i = tid; i < NSEG; i += 256) {
        int h = hist[i];
        if (h) atomicAdd(&counts[b * NSEG + i], h);
    }
    if (tid == 0) atomicMax(&ws[OFF_MAX], bmax);
}

// Segment-sum accumulation. grid = NB*NCG*CHUNKS = 512 blocks of 1024.
// LDS table [NSEG][CG] fp32 = 64 KB, swizzled slot: l*CG + ((c+l)&15).
__global__ __launch_bounds__(1024, 8)
void k_accum(const float* __restrict__ inp, const int* __restrict__ sup,
             float* __restrict__ ws) {
    __shared__ float tbl[NSEG * CG];
    const int tid = threadIdx.x;
    const int bid = blockIdx.x;
    const int chunk = bid & 31;
    const int cgb   = bid >> 5;
    const int cg    = cgb & 3;
    const int b     = cgb >> 2;

    for (int i = tid; i < NSEG * CG; i += 1024) tbl[i] = 0.f;
    __syncthreads();

    const int pbase = chunk * CHUNK_PIX;
    const int* supb = sup + (size_t)b * HW;

    #pragma unroll
    for (int it = 0; it < CHUNK_PIX / (1024 * 4); ++it) {   // 2 iters
        const int p0 = pbase + (it * 1024 + tid) * 4;
        int4 l4 = *(const int4*)(supb + p0);
        int l0 = l4.x, l1 = l4.y, l2 = l4.z, l3 = l4.w;
        #pragma unroll
        for (int c16 = 0; c16 < CG; ++c16) {
            const int c = cg * CG + c16;
            float4 v = *(const float4*)(inp + ((size_t)(b * NC + c)) * HW + p0);
            atomicAdd(&tbl[l0 * CG + ((c16 + l0) & 15)], v.x);
            atomicAdd(&tbl[l1 * CG + ((c16 + l1) & 15)], v.y);
            atomicAdd(&tbl[l2 * CG + ((c16 + l2) & 15)], v.z);
            atomicAdd(&tbl[l3 * CG + ((c16 + l3) & 15)], v.w);
        }
    }
    __syncthreads();

    float* sums = (float*)ws + OFF_SUMS;
    for (int e = tid; e < NSEG * CG; e += 1024) {
        const int seg = e >> 4;
        const int j   = e & 15;
        const int c16 = (j - seg) & 15;
        const float v = tbl[e];
        if (v != 0.f)
            atomicAdd(&sums[((size_t)(b * NSEG + seg)) * NC + cg * CG + c16], v);
    }
}

// scaled[s*64+c] = (l < maxele) ? WEIGHT * sums / (cnt + EPS) : 0
__global__ void k_means(float* __restrict__ ws) {
    const int idx = blockIdx.x * 256 + threadIdx.x;   // < BK*NC
    const float* sums   = ws + OFF_SUMS;
    const int*   counts = (const int*)ws + OFF_CNT;
    const int    maxele = ((const int*)ws)[OFF_MAX];
    float* scaled = ws + OFF_SCALED;
    const int s = idx >> 6;
    const int l = s & (NSEG - 1);
    const float cnt = (float)counts[s];
    const float m = WEIGHT * sums[idx] / (cnt + EPSV);
    scaled[idx] = (l < maxele) ? m : 0.f;
}

// Apply: out = inp + scaled[seg][c]. Same decomposition/swizzle as k_accum.
__global__ __launch_bounds__(1024, 8)
void k_apply(const float* __restrict__ inp, const int* __restrict__ sup,
             const float* __restrict__ ws, float* __restrict__ out) {
    __shared__ float tbl[NSEG * CG];
    const int tid = threadIdx.x;
    const int bid = blockIdx.x;
    const int chunk = bid & 31;
    const int cgb   = bid >> 5;
    const int cg    = cgb & 3;
    const int b     = cgb >> 2;

    const float* scaled = ws + OFF_SCALED;
    for (int e = tid; e < NSEG * CG; e += 1024) {
        const int seg = e >> 4;
        const int j   = e & 15;
        const int c16 = (j - seg) & 15;
        tbl[e] = scaled[((size_t)(b * NSEG + seg)) * NC + cg * CG + c16];
    }
    __syncthreads();

    const int pbase = chunk * CHUNK_PIX;
    const int* supb = sup + (size_t)b * HW;

    #pragma unroll
    for (int it = 0; it < CHUNK_PIX / (1024 * 4); ++it) {   // 2 iters
        const int p0 = pbase + (it * 1024 + tid) * 4;
        int4 l4 = *(const int4*)(supb + p0);
        int l0 = l4.x, l1 = l4.y, l2 = l4.z, l3 = l4.w;
        #pragma unroll
        for (int c16 = 0; c16 < CG; ++c16) {
            const size_t gidx = ((size_t)(b * NC + cg * CG + c16)) * HW + p0;
            float4 v = *(const float4*)(inp + gidx);
            v.x += tbl[l0 * CG + ((c16 + l0) & 15)];
            v.y += tbl[l1 * CG + ((c16 + l1) & 15)];
            v.z += tbl[l2 * CG + ((c16 + l2) & 15)];
            v.w += tbl[l3 * CG + ((c16 + l3) & 15)];
            *(float4*)(out + gidx) = v;
        }
    }
}

extern "C" void kernel_launch(void* const* d_in, const int* in_sizes, int n_in,
                              void* d_out, int out_size, void* d_ws, size_t ws_size,
                              hipStream_t stream) {
    const float* inp = (const float*)d_in[0];
    const int*   sup = (const int*)d_in[1];
    float* out = (float*)d_out;
    float* ws  = (float*)d_ws;

    k_zero<<<512, 256, 0, stream>>>((unsigned int*)d_ws);
    k_hist<<<NB * 128, 256, 0, stream>>>(sup, (int*)d_ws);
    k_accum<<<NB * NCG * CHUNKS, 1024, 0, stream>>>(inp, sup, ws);
    k_means<<<(BK * NC) / 256, 256, 0, stream>>>(ws);
    k_apply<<<NB * NCG * CHUNKS, 1024, 0, stream>>>(inp, sup, ws, out);
}